// Round 3
// baseline (80.188 us; speedup 1.0000x reference)
//
#include <hip/hip_runtime.h>

// Spread a 16-bit plane slice to stride-4 positions with bit-reversal:
// input s (16 bits, bit i = element-bit j=4i+p), output bit (60-4i) = s.bit i.
// Caller shifts left by (3-p) to place plane p at IEEE position 63-(4i+p).
__device__ __forceinline__ unsigned long long spread4_rev16(unsigned int s) {
    unsigned long long x = (unsigned long long)(__brev(s) >> 16); // bit(15-i) = s.bit i
    x = (x | (x << 24)) & 0x000000FF000000FFull;
    x = (x | (x << 12)) & 0x000F000F000F000Full;
    x = (x | (x << 6 )) & 0x0303030303030303ull;
    x = (x | (x << 3 )) & 0x1111111111111111ull;  // bit m -> bit 4m
    return x;
}

// Bit-exact integer reimplementation of the reference's fp64->fp32 circuit.
// d = IEEE-754 double bit pattern (bit 63 = reference's MSB-first float 0).
// Mux priority per reference: nan > inf > underflow > overflow > normal.
__device__ __forceinline__ unsigned int fp64bits_to_fp32bits(unsigned long long d) {
    const unsigned int sign  = (unsigned int)(d >> 63);
    const unsigned int exp11 = (unsigned int)(d >> 52) & 0x7FFu;
    const unsigned long long mant52 = d & 0x000FFFFFFFFFFFFFull;

    const bool e_all = (exp11 == 0x7FFu);
    const bool m_any = (mant52 != 0ull);

    const unsigned int exp8   = (exp11 - 896u) & 0xFFu;       // 11-bit sub, low 8
    const unsigned int mant23 = (unsigned int)(mant52 >> 29); // top 23 mant bits
    const unsigned int L = mant23 & 1u;
    const unsigned int R = (unsigned int)(mant52 >> 28) & 1u;
    const unsigned int S = ((mant52 & 0x0FFFFFFFull) != 0ull) ? 1u : 0u;
    const unsigned int rup    = R & (S | L);
    const unsigned int mant24 = mant23 + rup;
    const unsigned int carry  = mant24 >> 23;
    const unsigned int mant   = mant24 & 0x7FFFFFu;
    const unsigned int fexp   = (exp8 + carry) & 0xFFu;

    unsigned int res = (sign << 31) | (fexp << 23) | mant;
    const unsigned int sgn31 = sign << 31;
    if (exp11 > 1150u)   res = sgn31 | 0x7F800000u;  // overflow -> inf
    if (exp11 < 897u)    res = sgn31;                // underflow -> signed zero
    if (e_all && !m_any) res = sgn31 | 0x7F800000u;  // inf
    if (e_all &&  m_any) res = sgn31 | 0x7FC00000u;  // nan
    return res;
}

// One wave handles 16 elements per iteration, all streams 16 B/lane:
//   - 4 float4 loads (1 KB each, fully coalesced): lane l of load k holds
//     element 4k+(l>>4), bits 4*(l&15)..+3 (MSB-first pulse order)
//   - 4 bit-plane ballots per load: ballot bit l = plane-p bit (l&15) of
//     element 4k+(l>>4)   (plane p = component p of the float4)
//   - per lane: select its two target elements' 16-bit plane slices,
//     rev16+spread4 to assemble the IEEE fp64 bit pattern, convert on VALU
//   - 2 float4 stores per lane (2 * 256 floats = 16 * 32 output bits)
__global__ void __launch_bounds__(256) fp64_to_fp32_pulse_kernel(
        const float* __restrict__ in, float* __restrict__ out, int nElems)
{
    const int lane   = (int)(threadIdx.x & 63u);
    const int wave   = (int)((blockIdx.x * blockDim.x + threadIdx.x) >> 6);
    const int nWaves = (int)((gridDim.x * blockDim.x) >> 6);

    const bool hi  = (lane & 32) != 0;          // which load of the pair
    const int  s16 = (lane & 24) << 1;          // 16*((lane>>3)&3): quadrant shift
    const int  sh  = 28 - ((lane & 7) << 2);    // output nibble shift

    const int nG = nElems >> 4;                 // 16 elements per group
    const float4* __restrict__ in4 = reinterpret_cast<const float4*>(in);

    for (int g = wave; g < nG; g += nWaves) {
        const float4* __restrict__ p = in4 + ((long long)g << 8) + lane; // g*256

        const float4 qa = p[0];     // elements g*16 + 0..3
        const float4 qb = p[64];    // elements g*16 + 4..7
        const float4 qc = p[128];   // elements g*16 + 8..11
        const float4 qd = p[192];   // elements g*16 + 12..15

        const unsigned long long P0a = __ballot(qa.x != 0.0f);
        const unsigned long long P1a = __ballot(qa.y != 0.0f);
        const unsigned long long P2a = __ballot(qa.z != 0.0f);
        const unsigned long long P3a = __ballot(qa.w != 0.0f);
        const unsigned long long P0b = __ballot(qb.x != 0.0f);
        const unsigned long long P1b = __ballot(qb.y != 0.0f);
        const unsigned long long P2b = __ballot(qb.z != 0.0f);
        const unsigned long long P3b = __ballot(qb.w != 0.0f);
        const unsigned long long P0c = __ballot(qc.x != 0.0f);
        const unsigned long long P1c = __ballot(qc.y != 0.0f);
        const unsigned long long P2c = __ballot(qc.z != 0.0f);
        const unsigned long long P3c = __ballot(qc.w != 0.0f);
        const unsigned long long P0d = __ballot(qd.x != 0.0f);
        const unsigned long long P1d = __ballot(qd.y != 0.0f);
        const unsigned long long P2d = __ballot(qd.z != 0.0f);
        const unsigned long long P3d = __ballot(qd.w != 0.0f);

        // lane's targets: e0 = g*16 + (lane>>3) (in loads a/b),
        //                 e1 = e0 + 8           (in loads c/d)
        const unsigned long long B0 = hi ? P0b : P0a;
        const unsigned long long B1 = hi ? P1b : P1a;
        const unsigned long long B2 = hi ? P2b : P2a;
        const unsigned long long B3 = hi ? P3b : P3a;
        const unsigned long long C0 = hi ? P0d : P0c;
        const unsigned long long C1 = hi ? P1d : P1c;
        const unsigned long long C2 = hi ? P2d : P2c;
        const unsigned long long C3 = hi ? P3d : P3c;

        const unsigned int s0 = (unsigned int)(B0 >> s16) & 0xFFFFu;
        const unsigned int s1 = (unsigned int)(B1 >> s16) & 0xFFFFu;
        const unsigned int s2 = (unsigned int)(B2 >> s16) & 0xFFFFu;
        const unsigned int s3 = (unsigned int)(B3 >> s16) & 0xFFFFu;
        const unsigned int t0 = (unsigned int)(C0 >> s16) & 0xFFFFu;
        const unsigned int t1 = (unsigned int)(C1 >> s16) & 0xFFFFu;
        const unsigned int t2 = (unsigned int)(C2 >> s16) & 0xFFFFu;
        const unsigned int t3 = (unsigned int)(C3 >> s16) & 0xFFFFu;

        const unsigned long long d0 = (spread4_rev16(s0) << 3)
                                    | (spread4_rev16(s1) << 2)
                                    | (spread4_rev16(s2) << 1)
                                    |  spread4_rev16(s3);
        const unsigned long long d1 = (spread4_rev16(t0) << 3)
                                    | (spread4_rev16(t1) << 2)
                                    | (spread4_rev16(t2) << 1)
                                    |  spread4_rev16(t3);

        const unsigned int r0 = fp64bits_to_fp32bits(d0);
        const unsigned int r1 = fp64bits_to_fp32bits(d1);

        const unsigned int nib0 = (r0 >> sh) & 0xFu;
        const unsigned int nib1 = (r1 >> sh) & 0xFu;

        float4 o0, o1;
        o0.x = (float)((nib0 >> 3) & 1u);
        o0.y = (float)((nib0 >> 2) & 1u);
        o0.z = (float)((nib0 >> 1) & 1u);
        o0.w = (float)( nib0       & 1u);
        o1.x = (float)((nib1 >> 3) & 1u);
        o1.y = (float)((nib1 >> 2) & 1u);
        o1.z = (float)((nib1 >> 1) & 1u);
        o1.w = (float)( nib1       & 1u);

        float* __restrict__ q = out + ((long long)g << 9) + (lane << 2);
        *reinterpret_cast<float4*>(q)       = o0;
        *reinterpret_cast<float4*>(q + 256) = o1;
    }

    // tail: whole elements one at a time (empty for B = 1048576)
    const int tailStart = nG << 4;
    for (int e = tailStart + wave; e < nElems; e += nWaves) {
        const float v = in[(long long)e * 64 + lane];
        const unsigned long long mm = __ballot(v != 0.0f);
        const unsigned int r = fp64bits_to_fp32bits(__brevll(mm));
        if (lane < 32) {
            out[(long long)e * 32 + lane] = (float)((r >> (31 - lane)) & 1u);
        }
    }
}

extern "C" void kernel_launch(void* const* d_in, const int* in_sizes, int n_in,
                              void* d_out, int out_size, void* d_ws, size_t ws_size,
                              hipStream_t stream) {
    (void)n_in; (void)d_ws; (void)ws_size; (void)out_size;
    const float* in = (const float*)d_in[0];
    float* out = (float*)d_out;

    const int nElems = in_sizes[0] / 64;   // 1048576 for this problem
    const int threads = 256;               // 4 waves/block
    const int nG = nElems >> 4;
    const int wavesPerBlock = threads / 64;
    int blocks = (nG + wavesPerBlock - 1) / wavesPerBlock;
    if (blocks > 2048) blocks = 2048;      // grid-stride the rest
    if (blocks < 1) blocks = 1;

    fp64_to_fp32_pulse_kernel<<<blocks, threads, 0, stream>>>(in, out, nElems);
}

// Round 5
// 61.583 us; speedup vs baseline: 1.3021x; 1.3021x over previous
//
#include <hip/hip_runtime.h>

typedef float __attribute__((ext_vector_type(4))) floatx4; // clang native vec:
// accepted by __builtin_nontemporal_store (HIP_vector_type float4 is not)

// Spread a 16-bit plane slice to stride-4 positions with bit-reversal:
// input s (16 bits, bit i = element-bit j=4i+p), output bit (60-4i) = s.bit i.
// Caller shifts left by (3-p) to place plane p at IEEE position 63-(4i+p).
__device__ __forceinline__ unsigned long long spread4_rev16(unsigned int s) {
    unsigned long long x = (unsigned long long)(__brev(s) >> 16); // bit(15-i) = s.bit i
    x = (x | (x << 24)) & 0x000000FF000000FFull;
    x = (x | (x << 12)) & 0x000F000F000F000Full;
    x = (x | (x << 6 )) & 0x0303030303030303ull;
    x = (x | (x << 3 )) & 0x1111111111111111ull;  // bit m -> bit 4m
    return x;
}

// Bit-exact integer reimplementation of the reference's fp64->fp32 circuit.
// d = IEEE-754 double bit pattern (bit 63 = reference's MSB-first float 0).
// Mux priority per reference: nan > inf > underflow > overflow > normal.
__device__ __forceinline__ unsigned int fp64bits_to_fp32bits(unsigned long long d) {
    const unsigned int sign  = (unsigned int)(d >> 63);
    const unsigned int exp11 = (unsigned int)(d >> 52) & 0x7FFu;
    const unsigned long long mant52 = d & 0x000FFFFFFFFFFFFFull;

    const bool e_all = (exp11 == 0x7FFu);
    const bool m_any = (mant52 != 0ull);

    const unsigned int exp8   = (exp11 - 896u) & 0xFFu;       // 11-bit sub, low 8
    const unsigned int mant23 = (unsigned int)(mant52 >> 29); // top 23 mant bits
    const unsigned int L = mant23 & 1u;
    const unsigned int R = (unsigned int)(mant52 >> 28) & 1u;
    const unsigned int S = ((mant52 & 0x0FFFFFFFull) != 0ull) ? 1u : 0u;
    const unsigned int rup    = R & (S | L);
    const unsigned int mant24 = mant23 + rup;
    const unsigned int carry  = mant24 >> 23;
    const unsigned int mant   = mant24 & 0x7FFFFFu;
    const unsigned int fexp   = (exp8 + carry) & 0xFFu;

    unsigned int res = (sign << 31) | (fexp << 23) | mant;
    const unsigned int sgn31 = sign << 31;
    if (exp11 > 1150u)   res = sgn31 | 0x7F800000u;  // overflow -> inf
    if (exp11 < 897u)    res = sgn31;                // underflow -> signed zero
    if (e_all && !m_any) res = sgn31 | 0x7F800000u;  // inf
    if (e_all &&  m_any) res = sgn31 | 0x7FC00000u;  // nan
    return res;
}

// One wave handles 16 elements per iteration, all streams 16 B/lane.
// Output uses NONTEMPORAL stores: the write stream is write-once/never-read;
// streaming stores avoid the write-allocate RFO fetch (~128 MiB) that was
// saturating HBM at 512 MiB effective traffic instead of 384 MiB.
__global__ void __launch_bounds__(256) fp64_to_fp32_pulse_kernel(
        const float* __restrict__ in, float* __restrict__ out, int nElems)
{
    const int lane   = (int)(threadIdx.x & 63u);
    const int wave   = (int)((blockIdx.x * blockDim.x + threadIdx.x) >> 6);
    const int nWaves = (int)((gridDim.x * blockDim.x) >> 6);

    const bool hi  = (lane & 32) != 0;          // which load of the pair
    const int  s16 = (lane & 24) << 1;          // 16*((lane>>3)&3): quadrant shift
    const int  sh  = 28 - ((lane & 7) << 2);    // output nibble shift

    const int nG = nElems >> 4;                 // 16 elements per group
    const float4* __restrict__ in4 = reinterpret_cast<const float4*>(in);

    for (int g = wave; g < nG; g += nWaves) {
        const float4* __restrict__ p = in4 + ((long long)g << 8) + lane; // g*256

        const float4 qa = p[0];     // elements g*16 + 0..3
        const float4 qb = p[64];    // elements g*16 + 4..7
        const float4 qc = p[128];   // elements g*16 + 8..11
        const float4 qd = p[192];   // elements g*16 + 12..15

        const unsigned long long P0a = __ballot(qa.x != 0.0f);
        const unsigned long long P1a = __ballot(qa.y != 0.0f);
        const unsigned long long P2a = __ballot(qa.z != 0.0f);
        const unsigned long long P3a = __ballot(qa.w != 0.0f);
        const unsigned long long P0b = __ballot(qb.x != 0.0f);
        const unsigned long long P1b = __ballot(qb.y != 0.0f);
        const unsigned long long P2b = __ballot(qb.z != 0.0f);
        const unsigned long long P3b = __ballot(qb.w != 0.0f);
        const unsigned long long P0c = __ballot(qc.x != 0.0f);
        const unsigned long long P1c = __ballot(qc.y != 0.0f);
        const unsigned long long P2c = __ballot(qc.z != 0.0f);
        const unsigned long long P3c = __ballot(qc.w != 0.0f);
        const unsigned long long P0d = __ballot(qd.x != 0.0f);
        const unsigned long long P1d = __ballot(qd.y != 0.0f);
        const unsigned long long P2d = __ballot(qd.z != 0.0f);
        const unsigned long long P3d = __ballot(qd.w != 0.0f);

        // lane's targets: e0 = g*16 + (lane>>3) (in loads a/b),
        //                 e1 = e0 + 8           (in loads c/d)
        const unsigned long long B0 = hi ? P0b : P0a;
        const unsigned long long B1 = hi ? P1b : P1a;
        const unsigned long long B2 = hi ? P2b : P2a;
        const unsigned long long B3 = hi ? P3b : P3a;
        const unsigned long long C0 = hi ? P0d : P0c;
        const unsigned long long C1 = hi ? P1d : P1c;
        const unsigned long long C2 = hi ? P2d : P2c;
        const unsigned long long C3 = hi ? P3d : P3c;

        const unsigned int s0 = (unsigned int)(B0 >> s16) & 0xFFFFu;
        const unsigned int s1 = (unsigned int)(B1 >> s16) & 0xFFFFu;
        const unsigned int s2 = (unsigned int)(B2 >> s16) & 0xFFFFu;
        const unsigned int s3 = (unsigned int)(B3 >> s16) & 0xFFFFu;
        const unsigned int t0 = (unsigned int)(C0 >> s16) & 0xFFFFu;
        const unsigned int t1 = (unsigned int)(C1 >> s16) & 0xFFFFu;
        const unsigned int t2 = (unsigned int)(C2 >> s16) & 0xFFFFu;
        const unsigned int t3 = (unsigned int)(C3 >> s16) & 0xFFFFu;

        const unsigned long long d0 = (spread4_rev16(s0) << 3)
                                    | (spread4_rev16(s1) << 2)
                                    | (spread4_rev16(s2) << 1)
                                    |  spread4_rev16(s3);
        const unsigned long long d1 = (spread4_rev16(t0) << 3)
                                    | (spread4_rev16(t1) << 2)
                                    | (spread4_rev16(t2) << 1)
                                    |  spread4_rev16(t3);

        const unsigned int r0 = fp64bits_to_fp32bits(d0);
        const unsigned int r1 = fp64bits_to_fp32bits(d1);

        const unsigned int nib0 = (r0 >> sh) & 0xFu;
        const unsigned int nib1 = (r1 >> sh) & 0xFu;

        floatx4 o0, o1;
        o0.x = (float)((nib0 >> 3) & 1u);
        o0.y = (float)((nib0 >> 2) & 1u);
        o0.z = (float)((nib0 >> 1) & 1u);
        o0.w = (float)( nib0       & 1u);
        o1.x = (float)((nib1 >> 3) & 1u);
        o1.y = (float)((nib1 >> 2) & 1u);
        o1.z = (float)((nib1 >> 1) & 1u);
        o1.w = (float)( nib1       & 1u);

        floatx4* q = reinterpret_cast<floatx4*>(out + ((long long)g << 9)) + lane;
        __builtin_nontemporal_store(o0, q);        // streaming store, no RFO
        __builtin_nontemporal_store(o1, q + 64);   // +256 floats
    }

    // tail: whole elements one at a time (empty for B = 1048576)
    const int tailStart = nG << 4;
    for (int e = tailStart + wave; e < nElems; e += nWaves) {
        const float v = in[(long long)e * 64 + lane];
        const unsigned long long mm = __ballot(v != 0.0f);
        const unsigned int r = fp64bits_to_fp32bits(__brevll(mm));
        if (lane < 32) {
            out[(long long)e * 32 + lane] = (float)((r >> (31 - lane)) & 1u);
        }
    }
}

extern "C" void kernel_launch(void* const* d_in, const int* in_sizes, int n_in,
                              void* d_out, int out_size, void* d_ws, size_t ws_size,
                              hipStream_t stream) {
    (void)n_in; (void)d_ws; (void)ws_size; (void)out_size;
    const float* in = (const float*)d_in[0];
    float* out = (float*)d_out;

    const int nElems = in_sizes[0] / 64;   // 1048576 for this problem
    const int threads = 256;               // 4 waves/block
    const int nG = nElems >> 4;
    const int wavesPerBlock = threads / 64;
    int blocks = (nG + wavesPerBlock - 1) / wavesPerBlock;
    if (blocks > 2048) blocks = 2048;      // grid-stride the rest
    if (blocks < 1) blocks = 1;

    fp64_to_fp32_pulse_kernel<<<blocks, threads, 0, stream>>>(in, out, nElems);
}